// Round 7
// baseline (64.931 us; speedup 1.0000x reference)
//
#include <hip/hip_runtime.h>
#include <hip/hip_bf16.h>
#include <stdint.h>

// Problem constants (B,S,D,K) = (2,4096,512,32)
#define S_LEN  4096
#define D_DIM  512
#define K_R    32
#define M_ROWS 8192

typedef __attribute__((ext_vector_type(8))) short bf16x8;
typedef __attribute__((ext_vector_type(4))) float f32x4;

__device__ __forceinline__ float bf2f(short u) {
  union { unsigned int i; float f; } c;
  c.i = ((unsigned int)(unsigned short)u) << 16;
  return c.f;
}

__device__ __forceinline__ void gload_lds16(const void* g, void* lds) {
  __builtin_amdgcn_global_load_lds(
      (__attribute__((address_space(1))) void*)g,
      (__attribute__((address_space(3))) void*)lds, 16, 0, 0);
}

__device__ __forceinline__ int4 pack8(float4 v0, float4 v1) {
  union { __hip_bfloat16 h[8]; int4 v; } u;
  u.h[0] = __float2bfloat16(v0.x); u.h[1] = __float2bfloat16(v0.y);
  u.h[2] = __float2bfloat16(v0.z); u.h[3] = __float2bfloat16(v0.w);
  u.h[4] = __float2bfloat16(v1.x); u.h[5] = __float2bfloat16(v1.y);
  u.h[6] = __float2bfloat16(v1.z); u.h[7] = __float2bfloat16(v1.w);
  return u.v;
}

#define BM 128
#define BN 64
#define BK 64

// ---------------------------------------------------------------------------
// Kernel 1 (prep): R4-proven verbatim.
//   blocks [0,2048): cast x->bf16. [2048,2112): W_in->bf16. [2112,2176):
//   transpose-cast W_out -> WoutTb.
// ---------------------------------------------------------------------------
__global__ void __launch_bounds__(256) prep_kernel(
    const float* __restrict__ x, __hip_bfloat16* __restrict__ xb,
    const float* __restrict__ Win, __hip_bfloat16* __restrict__ Winb,
    const float* __restrict__ Wout, __hip_bfloat16* __restrict__ WoutTb) {
  __shared__ __hip_bfloat16 Lds[64][66];
  const int tid = threadIdx.x;
  if (blockIdx.x < 2048) {
    const int i = blockIdx.x * 256 + tid;
    const float4* xp = (const float4*)x;
    ((int4*)xb)[i] = pack8(xp[2 * i], xp[2 * i + 1]);
    return;
  }
  if (blockIdx.x < 2112) {
    const int e4 = ((blockIdx.x - 2048) * 256 + tid) * 4;
    const float4* wp = (const float4*)Win;
    int4* op = (int4*)Winb;
#pragma unroll
    for (int h = 0; h < 2; ++h)
      op[e4 / 2 + h] = pack8(wp[e4 + 2 * h], wp[e4 + 2 * h + 1]);
    return;
  }
  const int bx = blockIdx.x - 2112;
  const int tr = (bx >> 3) * 64;
  const int tc = (bx & 7) * 64;
#pragma unroll
  for (int it = 0; it < 4; ++it) {
    const int id = it * 256 + tid;
    const int r = id >> 4, c4 = (id & 15) * 4;
    const float4 v = *(const float4*)&Wout[(size_t)(tr + r) * 512 + tc + c4];
    Lds[r][c4]     = __float2bfloat16(v.x);
    Lds[r][c4 + 1] = __float2bfloat16(v.y);
    Lds[r][c4 + 2] = __float2bfloat16(v.z);
    Lds[r][c4 + 3] = __float2bfloat16(v.w);
  }
  __syncthreads();
#pragma unroll
  for (int it = 0; it < 2; ++it) {
    const int id = it * 256 + tid;
    const int j = id >> 3, i0 = (id & 7) * 8;
    union { __hip_bfloat16 h[8]; int4 v; } u;
#pragma unroll
    for (int r = 0; r < 8; ++r) u.h[r] = Lds[i0 + r][j];
    *(int4*)&WoutTb[(size_t)(tc + j) * 512 + tr + i0] = u.v;
  }
}

// ---------------------------------------------------------------------------
// Kernel 2 (wc): R4-proven verbatim. WcT[j][q] = sum_p WoutTb[j][p]*Winb[q][p]
// ---------------------------------------------------------------------------
__global__ void __launch_bounds__(256) wc_kernel(
    const __hip_bfloat16* __restrict__ WoutTb,
    const __hip_bfloat16* __restrict__ Winb,
    __hip_bfloat16* __restrict__ WcT) {
  __shared__ __hip_bfloat16 As[BM][BK];
  __shared__ __hip_bfloat16 Bs[BN][BK];
  const int tid = threadIdx.x;
  const int w = tid >> 6, l = tid & 63;

  const int id2 = blockIdx.x;
  const int bm0 = (id2 >> 3) * BM;
  const int bn0 = (id2 & 7) * BN;
  const int wr  = (w >> 1) * 64;
  const int wcn = (w & 1) * 32;

  const int rin = l >> 3;
  const int usw = (l & 7) ^ rin;
  const __hip_bfloat16* gA = WoutTb + (size_t)(bm0 + w * 8 + rin) * D_DIM + usw * 8;
  const __hip_bfloat16* gB = Winb   + (size_t)(bn0 + w * 8 + rin) * D_DIM + usw * 8;
  __hip_bfloat16* ldsA = &As[w * 8][0];
  __hip_bfloat16* ldsB = &Bs[w * 8][0];
  const int fr = l & 15, fq = l >> 4;

  f32x4 acc[4][2] = {};
  for (int k0 = 0; k0 < D_DIM; k0 += BK) {
#pragma unroll
    for (int i = 0; i < 4; ++i)
      gload_lds16(gA + (size_t)(i * 32) * D_DIM + k0, ldsA + i * 32 * BK);
#pragma unroll
    for (int j = 0; j < 2; ++j)
      gload_lds16(gB + (size_t)(j * 32) * D_DIM + k0, ldsB + j * 32 * BK);
    __syncthreads();
#pragma unroll
    for (int kk = 0; kk < 2; ++kk) {
      const int u = (kk * 4 + fq) ^ (fr & 7);
      bf16x8 af[4], bfv[2];
#pragma unroll
      for (int m = 0; m < 4; ++m)
        af[m] = *(const bf16x8*)&As[wr + m * 16 + fr][u * 8];
#pragma unroll
      for (int n = 0; n < 2; ++n)
        bfv[n] = *(const bf16x8*)&Bs[wcn + n * 16 + fr][u * 8];
#pragma unroll
      for (int m = 0; m < 4; ++m)
#pragma unroll
        for (int n = 0; n < 2; ++n)
          acc[m][n] = __builtin_amdgcn_mfma_f32_16x16x32_bf16(af[m], bfv[n], acc[m][n], 0, 0, 0);
    }
    __syncthreads();
  }
#pragma unroll
  for (int m = 0; m < 4; ++m)
#pragma unroll
    for (int n = 0; n < 2; ++n)
#pragma unroll
      for (int r = 0; r < 4; ++r) {
        const int grow = bm0 + wr + m * 16 + fq * 4 + r;
        const int gcol = bn0 + wcn + n * 16 + fr;
        WcT[(size_t)grow * D_DIM + gcol] = __float2bfloat16(acc[m][n][r]);
      }
}

// ---------------------------------------------------------------------------
// Kernel 3 (fused): block = 32 consecutive output rows.
//   Phase 1: gather-fuse rows (f32 acc) -> As[32][512] bf16 (XOR-swizzled).
//   Phase 2: out[rows][:] = As @ Wc + x + b_out, 8 strips of 64 cols,
//            double-buffered 8KB WcT tiles via global_load_lds.
// ---------------------------------------------------------------------------
__global__ void __launch_bounds__(256) fused_kernel(
    const __hip_bfloat16* __restrict__ Xb,
    const __hip_bfloat16* __restrict__ WcT,
    const float* __restrict__ x,
    const float* __restrict__ b_out,
    const float* __restrict__ fw,
    const int* __restrict__ routes,
    float* __restrict__ out) {
  __shared__ __hip_bfloat16 As[32 * 512];     // 32KB, unit-swizzled
  __shared__ __hip_bfloat16 Bs[2][64 * 64];   // 16KB
  __shared__ float w_s[32][33];               // padded: row stride 33 words
  __shared__ int   r_s[32][33];
  const int tid = threadIdx.x;
  const int w = tid >> 6, l = tid & 63;
  // XCD-chunked: 256 blocks = 8 XCDs x 32 contiguous row-groups
  const int id2 = (blockIdx.x & 7) * 32 + (blockIdx.x >> 3);
  const int m0 = id2 * 32;
  const int b  = m0 >> 12;              // batch (32 | 4096 -> uniform in block)
  const int s0 = m0 & (S_LEN - 1);

  // Phase 0: routes/weights for the 32 rows
#pragma unroll
  for (int it = 0; it < 4; ++it) {
    const int idx = it * 256 + tid;     // [0,1024)
    const int rl = idx >> 5, k = idx & 31;
    r_s[rl][k] = routes[(s0 + rl) * K_R + k];
    w_s[rl][k] = fw[(s0 + rl) * K_R + k];
  }
  __syncthreads();

  // Phase 1: gather. wave w: rows w*8..w*8+7; lane: (row, 16B-unit u8)
  {
    const int rl = w * 8 + (l >> 3);
    const int u8 = l & 7;
    float acc[64];
#pragma unroll
    for (int i = 0; i < 64; ++i) acc[i] = 0.f;
    const __hip_bfloat16* xbase = Xb + (size_t)b * S_LEN * D_DIM + u8 * 8;
    for (int k = 0; k < K_R; ++k) {
      const int   rt = r_s[rl][k];
      const float wk = w_s[rl][k];
      const bf16x8* p = (const bf16x8*)(xbase + (size_t)rt * D_DIM);
      bf16x8 v[8];
#pragma unroll
      for (int jj = 0; jj < 8; ++jj) v[jj] = p[jj * 8];   // units u8+8*jj
#pragma unroll
      for (int jj = 0; jj < 8; ++jj)
#pragma unroll
        for (int e = 0; e < 8; ++e)
          acc[jj * 8 + e] = fmaf(wk, bf2f(v[jj][e]), acc[jj * 8 + e]);
    }
    bf16x8* asrow = (bf16x8*)As + rl * 64;
    const int swz = u8 ^ (rl & 7);
#pragma unroll
    for (int jj = 0; jj < 8; ++jj) {
      union { __hip_bfloat16 h[8]; bf16x8 v; } u;
#pragma unroll
      for (int e = 0; e < 8; ++e) u.h[e] = __float2bfloat16(acc[jj * 8 + e]);
      asrow[jj * 8 + swz] = u.v;       // stored unit = logical ^ (row&7)
    }
  }
  __syncthreads();

  // Phase 2: GEMM + epilogue. 8 frags per strip: wave w -> (mi=w&1, ni=w>>1,+2)
  const int fr = l & 15, fq = l >> 4;
  const int mi = w & 1;
  const int ni = w >> 1;

#define STAGE_B(buf, tt)                                                      \
  {                                                                           \
    _Pragma("unroll")                                                         \
    for (int h = 0; h < 2; ++h) {                                             \
      const int idx = h * 256 + w * 64 + l;                                   \
      const int r = idx >> 3, u = idx & 7;                                    \
      const __hip_bfloat16* src = WcT + (size_t)(n0 + r) * D_DIM +            \
                                  (tt) * 64 + ((u ^ (r & 7)) * 8);            \
      gload_lds16(src, (__hip_bfloat16*)Bs[buf] + (h * 256 + w * 64) * 8);    \
    }                                                                         \
  }

  for (int n0 = 0; n0 < D_DIM; n0 += 64) {
    f32x4 c0 = {0.f, 0.f, 0.f, 0.f}, c1 = {0.f, 0.f, 0.f, 0.f};
    STAGE_B(0, 0);
    __syncthreads();
#pragma unroll
    for (int t = 0; t < 8; ++t) {
      if (t < 7) STAGE_B((t + 1) & 1, t + 1);
      const int buf = t & 1;
#pragma unroll
      for (int kk = 0; kk < 2; ++kk) {
        const int su = (kk * 4 + fq) ^ (fr & 7);
        const bf16x8 af  = ((const bf16x8*)As)[(mi * 16 + fr) * 64 + t * 8 + su];
        const bf16x8 b0v = ((const bf16x8*)Bs[buf])[(ni * 16 + fr) * 8 + su];
        const bf16x8 b1v = ((const bf16x8*)Bs[buf])[((ni + 2) * 16 + fr) * 8 + su];
        c0 = __builtin_amdgcn_mfma_f32_16x16x32_bf16(af, b0v, c0, 0, 0, 0);
        c1 = __builtin_amdgcn_mfma_f32_16x16x32_bf16(af, b1v, c1, 0, 0, 0);
      }
      __syncthreads();
    }
    // epilogue: C/D layout col = lane&15, row = fq*4 + reg
    const float bb0 = b_out[n0 + ni * 16 + fr];
    const float bb1 = b_out[n0 + ni * 16 + 32 + fr];
#pragma unroll
    for (int r = 0; r < 4; ++r) {
      const int grow = m0 + mi * 16 + fq * 4 + r;
      const size_t base = (size_t)grow * D_DIM + n0 + ni * 16 + fr;
      out[base]      = c0[r] + x[base]      + bb0;
      out[base + 32] = c1[r] + x[base + 32] + bb1;
    }
  }
#undef STAGE_B
}

// ---------------------------------------------------------------------------
extern "C" void kernel_launch(void* const* d_in, const int* in_sizes, int n_in,
                              void* d_out, int out_size, void* d_ws, size_t ws_size,
                              hipStream_t stream) {
  const float* x      = (const float*)d_in[0];
  const float* W_in   = (const float*)d_in[1];
  const float* W_out  = (const float*)d_in[2];
  const float* b_out  = (const float*)d_in[3];
  const float* fw     = (const float*)d_in[4];
  const int*   routes = (const int*)d_in[5];
  float* out = (float*)d_out;

  // workspace: Xb(8MB) | WcT(512KB) | Winb(512KB) | WoutTb(512KB)
  char* ws = (char*)d_ws;
  __hip_bfloat16* Xb     = (__hip_bfloat16*)ws;
  __hip_bfloat16* WcT    = (__hip_bfloat16*)(ws + 8388608);
  __hip_bfloat16* Winb   = (__hip_bfloat16*)(ws + 8912896);
  __hip_bfloat16* WoutTb = (__hip_bfloat16*)(ws + 9437184);

  // 1) casts + transpose (R4-proven)
  prep_kernel<<<2176, 256, 0, stream>>>(x, Xb, W_in, Winb, W_out, WoutTb);
  // 2) WcT (R4-proven, 32 blocks)
  wc_kernel<<<32, 256, 0, stream>>>(WoutTb, Winb, WcT);
  // 3) fused gather + GEMM + residual/bias epilogue
  fused_kernel<<<256, 256, 0, stream>>>(Xb, WcT, x, b_out, fw, routes, out);
}

// Round 8
// 48.534 us; speedup vs baseline: 1.3379x; 1.3379x over previous
//
#include <hip/hip_runtime.h>
#include <hip/hip_bf16.h>
#include <stdint.h>

// Problem constants (B,S,D,K) = (2,4096,512,32)
#define S_LEN  4096
#define D_DIM  512
#define K_R    32
#define M_ROWS 8192

typedef __attribute__((ext_vector_type(8))) short bf16x8;
typedef __attribute__((ext_vector_type(4))) float f32x4;

__device__ __forceinline__ float bf2f(short u) {
  union { unsigned int i; float f; } c;
  c.i = ((unsigned int)(unsigned short)u) << 16;
  return c.f;
}

__device__ __forceinline__ void gload_lds16(const void* g, void* lds) {
  __builtin_amdgcn_global_load_lds(
      (__attribute__((address_space(1))) void*)g,
      (__attribute__((address_space(3))) void*)lds, 16, 0, 0);
}

__device__ __forceinline__ int4 pack8(float4 v0, float4 v1) {
  union { __hip_bfloat16 h[8]; int4 v; } u;
  u.h[0] = __float2bfloat16(v0.x); u.h[1] = __float2bfloat16(v0.y);
  u.h[2] = __float2bfloat16(v0.z); u.h[3] = __float2bfloat16(v0.w);
  u.h[4] = __float2bfloat16(v1.x); u.h[5] = __float2bfloat16(v1.y);
  u.h[6] = __float2bfloat16(v1.z); u.h[7] = __float2bfloat16(v1.w);
  return u.v;
}

#define BM 128
#define BN 64
#define BK 64

// ---------------------------------------------------------------------------
// Kernel 1 (prep): R4-proven verbatim.
// ---------------------------------------------------------------------------
__global__ void __launch_bounds__(256) prep_kernel(
    const float* __restrict__ x, __hip_bfloat16* __restrict__ xb,
    const float* __restrict__ Win, __hip_bfloat16* __restrict__ Winb,
    const float* __restrict__ Wout, __hip_bfloat16* __restrict__ WoutTb) {
  __shared__ __hip_bfloat16 Lds[64][66];
  const int tid = threadIdx.x;
  if (blockIdx.x < 2048) {
    const int i = blockIdx.x * 256 + tid;
    const float4* xp = (const float4*)x;
    ((int4*)xb)[i] = pack8(xp[2 * i], xp[2 * i + 1]);
    return;
  }
  if (blockIdx.x < 2112) {
    const int e4 = ((blockIdx.x - 2048) * 256 + tid) * 4;
    const float4* wp = (const float4*)Win;
    int4* op = (int4*)Winb;
#pragma unroll
    for (int h = 0; h < 2; ++h)
      op[e4 / 2 + h] = pack8(wp[e4 + 2 * h], wp[e4 + 2 * h + 1]);
    return;
  }
  const int bx = blockIdx.x - 2112;
  const int tr = (bx >> 3) * 64;
  const int tc = (bx & 7) * 64;
#pragma unroll
  for (int it = 0; it < 4; ++it) {
    const int id = it * 256 + tid;
    const int r = id >> 4, c4 = (id & 15) * 4;
    const float4 v = *(const float4*)&Wout[(size_t)(tr + r) * 512 + tc + c4];
    Lds[r][c4]     = __float2bfloat16(v.x);
    Lds[r][c4 + 1] = __float2bfloat16(v.y);
    Lds[r][c4 + 2] = __float2bfloat16(v.z);
    Lds[r][c4 + 3] = __float2bfloat16(v.w);
  }
  __syncthreads();
#pragma unroll
  for (int it = 0; it < 2; ++it) {
    const int id = it * 256 + tid;
    const int j = id >> 3, i0 = (id & 7) * 8;
    union { __hip_bfloat16 h[8]; int4 v; } u;
#pragma unroll
    for (int r = 0; r < 8; ++r) u.h[r] = Lds[i0 + r][j];
    *(int4*)&WoutTb[(size_t)(tc + j) * 512 + tr + i0] = u.v;
  }
}

// ---------------------------------------------------------------------------
// Kernel 2 (wc): R4-proven verbatim. WcT[j][q] = sum_p WoutTb[j][p]*Winb[q][p]
// ---------------------------------------------------------------------------
__global__ void __launch_bounds__(256) wc_kernel(
    const __hip_bfloat16* __restrict__ WoutTb,
    const __hip_bfloat16* __restrict__ Winb,
    __hip_bfloat16* __restrict__ WcT) {
  __shared__ __hip_bfloat16 As[BM][BK];
  __shared__ __hip_bfloat16 Bs[BN][BK];
  const int tid = threadIdx.x;
  const int w = tid >> 6, l = tid & 63;

  const int id2 = blockIdx.x;
  const int bm0 = (id2 >> 3) * BM;
  const int bn0 = (id2 & 7) * BN;
  const int wr  = (w >> 1) * 64;
  const int wcn = (w & 1) * 32;

  const int rin = l >> 3;
  const int usw = (l & 7) ^ rin;
  const __hip_bfloat16* gA = WoutTb + (size_t)(bm0 + w * 8 + rin) * D_DIM + usw * 8;
  const __hip_bfloat16* gB = Winb   + (size_t)(bn0 + w * 8 + rin) * D_DIM + usw * 8;
  __hip_bfloat16* ldsA = &As[w * 8][0];
  __hip_bfloat16* ldsB = &Bs[w * 8][0];
  const int fr = l & 15, fq = l >> 4;

  f32x4 acc[4][2] = {};
  for (int k0 = 0; k0 < D_DIM; k0 += BK) {
#pragma unroll
    for (int i = 0; i < 4; ++i)
      gload_lds16(gA + (size_t)(i * 32) * D_DIM + k0, ldsA + i * 32 * BK);
#pragma unroll
    for (int j = 0; j < 2; ++j)
      gload_lds16(gB + (size_t)(j * 32) * D_DIM + k0, ldsB + j * 32 * BK);
    __syncthreads();
#pragma unroll
    for (int kk = 0; kk < 2; ++kk) {
      const int u = (kk * 4 + fq) ^ (fr & 7);
      bf16x8 af[4], bfv[2];
#pragma unroll
      for (int m = 0; m < 4; ++m)
        af[m] = *(const bf16x8*)&As[wr + m * 16 + fr][u * 8];
#pragma unroll
      for (int n = 0; n < 2; ++n)
        bfv[n] = *(const bf16x8*)&Bs[wcn + n * 16 + fr][u * 8];
#pragma unroll
      for (int m = 0; m < 4; ++m)
#pragma unroll
        for (int n = 0; n < 2; ++n)
          acc[m][n] = __builtin_amdgcn_mfma_f32_16x16x32_bf16(af[m], bfv[n], acc[m][n], 0, 0, 0);
    }
    __syncthreads();
  }
#pragma unroll
  for (int m = 0; m < 4; ++m)
#pragma unroll
    for (int n = 0; n < 2; ++n)
#pragma unroll
      for (int r = 0; r < 4; ++r) {
        const int grow = bm0 + wr + m * 16 + fq * 4 + r;
        const int gcol = bn0 + wcn + n * 16 + fr;
        WcT[(size_t)grow * D_DIM + gcol] = __float2bfloat16(acc[m][n][r]);
      }
}

// ---------------------------------------------------------------------------
// Kernel 3 (fused, 512 threads / 8 waves): block = 32 output rows.
//   Phase 1: gather-fuse 32 rows -> As[32][512] bf16, unit-swizzled.
//   Phase 2: wave w owns cols [w*64,(w+1)*64): A from LDS, B per-lane from
//            L2-resident WcT, NO barriers, fully unrolled K; epilogue fused.
// ---------------------------------------------------------------------------
__global__ void __launch_bounds__(512) fused_kernel(
    const __hip_bfloat16* __restrict__ Xb,
    const __hip_bfloat16* __restrict__ WcT,
    const float* __restrict__ x,
    const float* __restrict__ b_out,
    const float* __restrict__ fw,
    const int* __restrict__ routes,
    float* __restrict__ out) {
  __shared__ __hip_bfloat16 As[32 * 512];   // 32 KB, swizzled 16B units
  __shared__ int   r_s[32][33];             // padded
  __shared__ float w_s[32][33];
  const int tid = threadIdx.x;
  const int w = tid >> 6, l = tid & 63;
  // XCD-chunked: 256 blocks = 8 XCDs x 32 contiguous row-groups
  const int id2 = (blockIdx.x & 7) * 32 + (blockIdx.x >> 3);
  const int m0 = id2 * 32;
  const int b  = m0 >> 12;
  const int s0 = m0 & (S_LEN - 1);

  // Phase 0: routes/weights for the 32 rows (1024 entries / 512 threads)
#pragma unroll
  for (int it = 0; it < 2; ++it) {
    const int idx = it * 512 + tid;
    const int rl = idx >> 5, k = idx & 31;
    r_s[rl][k] = routes[(s0 + rl) * K_R + k];
    w_s[rl][k] = fw[(s0 + rl) * K_R + k];
  }
  __syncthreads();

  // Phase 1: gather. 8 waves x 4 rows; 16 lanes/row; lane units {l15 + 16j}
  {
    const int rl  = w * 4 + (l >> 4);
    const int l15 = l & 15;
    float acc[32];
#pragma unroll
    for (int i = 0; i < 32; ++i) acc[i] = 0.f;
    const bf16x8* xbat = (const bf16x8*)(Xb + (size_t)b * S_LEN * D_DIM);
#pragma unroll 4
    for (int k = 0; k < K_R; ++k) {
      const int   rt = r_s[rl][k];
      const float wk = w_s[rl][k];
      const bf16x8* p = xbat + (size_t)rt * 64;
      bf16x8 v[4];
#pragma unroll
      for (int j = 0; j < 4; ++j) v[j] = p[l15 + 16 * j];
#pragma unroll
      for (int j = 0; j < 4; ++j)
#pragma unroll
        for (int e = 0; e < 8; ++e)
          acc[j * 8 + e] = fmaf(wk, bf2f(v[j][e]), acc[j * 8 + e]);
    }
    bf16x8* asrow = (bf16x8*)As + rl * 64;
#pragma unroll
    for (int j = 0; j < 4; ++j) {
      union { __hip_bfloat16 h[8]; bf16x8 v; } u;
#pragma unroll
      for (int e = 0; e < 8; ++e) u.h[e] = __float2bfloat16(acc[j * 8 + e]);
      asrow[(l15 + 16 * j) ^ (rl & 7)] = u.v;   // stored unit = logical ^ (row&7)
    }
  }
  __syncthreads();

  // Phase 2: GEMM, barrier-free. wave w: cols n0..n0+63 (4 n-frags, 2 m-frags)
  const int fr = l & 15, fq = l >> 4;
  const int n0 = w * 64;
  f32x4 c0[4] = {}, c1[4] = {};
  const bf16x8* asv = (const bf16x8*)As;
#pragma unroll
  for (int ks = 0; ks < 16; ++ks) {
    const int su = (ks * 4 + fq) ^ (fr & 7);
    const bf16x8 a0 = asv[fr * 64 + su];           // rows 0..15
    const bf16x8 a1 = asv[(16 + fr) * 64 + su];    // rows 16..31
#pragma unroll
    for (int nf = 0; nf < 4; ++nf) {
      const bf16x8 bv = *(const bf16x8*)&WcT[(size_t)(n0 + nf * 16 + fr) * D_DIM +
                                             ks * 32 + fq * 8];
      c0[nf] = __builtin_amdgcn_mfma_f32_16x16x32_bf16(a0, bv, c0[nf], 0, 0, 0);
      c1[nf] = __builtin_amdgcn_mfma_f32_16x16x32_bf16(a1, bv, c1[nf], 0, 0, 0);
    }
  }

  // Epilogue: out = c + x + b_out.  C/D layout: col=fr, row=fq*4+reg.
#pragma unroll
  for (int nf = 0; nf < 4; ++nf) {
    const int col = n0 + nf * 16 + fr;
    const float bb = b_out[col];
#pragma unroll
    for (int r = 0; r < 4; ++r) {
      const size_t base0 = (size_t)(m0 + fq * 4 + r) * D_DIM + col;
      const size_t base1 = (size_t)(m0 + 16 + fq * 4 + r) * D_DIM + col;
      out[base0] = c0[nf][r] + x[base0] + bb;
      out[base1] = c1[nf][r] + x[base1] + bb;
    }
  }
}

// ---------------------------------------------------------------------------
extern "C" void kernel_launch(void* const* d_in, const int* in_sizes, int n_in,
                              void* d_out, int out_size, void* d_ws, size_t ws_size,
                              hipStream_t stream) {
  const float* x      = (const float*)d_in[0];
  const float* W_in   = (const float*)d_in[1];
  const float* W_out  = (const float*)d_in[2];
  const float* b_out  = (const float*)d_in[3];
  const float* fw     = (const float*)d_in[4];
  const int*   routes = (const int*)d_in[5];
  float* out = (float*)d_out;

  // workspace: Xb(8MB) | WcT(512KB) | Winb(512KB) | WoutTb(512KB)
  char* ws = (char*)d_ws;
  __hip_bfloat16* Xb     = (__hip_bfloat16*)ws;
  __hip_bfloat16* WcT    = (__hip_bfloat16*)(ws + 8388608);
  __hip_bfloat16* Winb   = (__hip_bfloat16*)(ws + 8912896);
  __hip_bfloat16* WoutTb = (__hip_bfloat16*)(ws + 9437184);

  // 1) casts + transpose (R4-proven)
  prep_kernel<<<2176, 256, 0, stream>>>(x, Xb, W_in, Winb, W_out, WoutTb);
  // 2) WcT (R4-proven, 32 blocks)
  wc_kernel<<<32, 256, 0, stream>>>(WoutTb, Winb, WcT);
  // 3) fused gather + barrier-free GEMM + residual/bias epilogue
  fused_kernel<<<256, 512, 0, stream>>>(Xb, WcT, x, b_out, fw, routes, out);
}

// Round 9
// 35.502 us; speedup vs baseline: 1.8289x; 1.3671x over previous
//
#include <hip/hip_runtime.h>
#include <hip/hip_bf16.h>
#include <stdint.h>

// Problem constants (B,S,D,K) = (2,4096,512,32)
#define S_LEN  4096
#define D_DIM  512
#define K_R    32
#define M_ROWS 8192

typedef __attribute__((ext_vector_type(8))) short bf16x8;
typedef __attribute__((ext_vector_type(4))) float f32x4;

__device__ __forceinline__ float bf2f(short u) {
  union { unsigned int i; float f; } c;
  c.i = ((unsigned int)(unsigned short)u) << 16;
  return c.f;
}

__device__ __forceinline__ void gload_lds16(const void* g, void* lds) {
  __builtin_amdgcn_global_load_lds(
      (__attribute__((address_space(1))) void*)g,
      (__attribute__((address_space(3))) void*)lds, 16, 0, 0);
}

__device__ __forceinline__ int4 pack8(float4 v0, float4 v1) {
  union { __hip_bfloat16 h[8]; int4 v; } u;
  u.h[0] = __float2bfloat16(v0.x); u.h[1] = __float2bfloat16(v0.y);
  u.h[2] = __float2bfloat16(v0.z); u.h[3] = __float2bfloat16(v0.w);
  u.h[4] = __float2bfloat16(v1.x); u.h[5] = __float2bfloat16(v1.y);
  u.h[6] = __float2bfloat16(v1.z); u.h[7] = __float2bfloat16(v1.w);
  return u.v;
}

// ---------------------------------------------------------------------------
// Kernel 1 (prep): R4-proven verbatim.
//   blocks [0,2048): cast x->bf16. [2048,2112): W_in->bf16. [2112,2176):
//   transpose-cast W_out -> WoutTb.
// ---------------------------------------------------------------------------
__global__ void __launch_bounds__(256) prep_kernel(
    const float* __restrict__ x, __hip_bfloat16* __restrict__ xb,
    const float* __restrict__ Win, __hip_bfloat16* __restrict__ Winb,
    const float* __restrict__ Wout, __hip_bfloat16* __restrict__ WoutTb) {
  __shared__ __hip_bfloat16 Lds[64][66];
  const int tid = threadIdx.x;
  if (blockIdx.x < 2048) {
    const int i = blockIdx.x * 256 + tid;
    const float4* xp = (const float4*)x;
    ((int4*)xb)[i] = pack8(xp[2 * i], xp[2 * i + 1]);
    return;
  }
  if (blockIdx.x < 2112) {
    const int e4 = ((blockIdx.x - 2048) * 256 + tid) * 4;
    const float4* wp = (const float4*)Win;
    int4* op = (int4*)Winb;
#pragma unroll
    for (int h = 0; h < 2; ++h)
      op[e4 / 2 + h] = pack8(wp[e4 + 2 * h], wp[e4 + 2 * h + 1]);
    return;
  }
  const int bx = blockIdx.x - 2112;
  const int tr = (bx >> 3) * 64;
  const int tc = (bx & 7) * 64;
#pragma unroll
  for (int it = 0; it < 4; ++it) {
    const int id = it * 256 + tid;
    const int r = id >> 4, c4 = (id & 15) * 4;
    const float4 v = *(const float4*)&Wout[(size_t)(tr + r) * 512 + tc + c4];
    Lds[r][c4]     = __float2bfloat16(v.x);
    Lds[r][c4 + 1] = __float2bfloat16(v.y);
    Lds[r][c4 + 2] = __float2bfloat16(v.z);
    Lds[r][c4 + 3] = __float2bfloat16(v.w);
  }
  __syncthreads();
#pragma unroll
  for (int it = 0; it < 2; ++it) {
    const int id = it * 256 + tid;
    const int j = id >> 3, i0 = (id & 7) * 8;
    union { __hip_bfloat16 h[8]; int4 v; } u;
#pragma unroll
    for (int r = 0; r < 8; ++r) u.h[r] = Lds[i0 + r][j];
    *(int4*)&WoutTb[(size_t)(tc + j) * 512 + tr + i0] = u.v;
  }
}

// ---------------------------------------------------------------------------
// Kernel 2 (mid): R4-proven verbatim.
//   blocks [0,32): wcgemm WcT = WoutTb x Winb (runs first, hides under gather)
//   blocks [32,2080): gather g[row,:] = sum_k w[s,k]*Xb[b,route,:]
// ---------------------------------------------------------------------------
#define BM 128
#define BN 64
#define BK 64

__global__ void __launch_bounds__(256) mid_kernel(
    const __hip_bfloat16* __restrict__ xb,
    const float* __restrict__ fw,
    const int* __restrict__ routes,
    __hip_bfloat16* __restrict__ g,
    const __hip_bfloat16* __restrict__ WoutTb,   // A  (m=j, k=p)
    const __hip_bfloat16* __restrict__ Winb,     // BT (n=q, k=p)
    __hip_bfloat16* __restrict__ WcT) {
  __shared__ __hip_bfloat16 As[BM][BK];   // 16 KB
  __shared__ __hip_bfloat16 Bs[BN][BK];   //  8 KB
  __shared__ float w_s[4][K_R];
  __shared__ int   r_s[4][K_R];
  const int tid = threadIdx.x;
  const int w = tid >> 6, l = tid & 63;

  if (blockIdx.x >= 32) {
    // ---- gather path ----
    const int lin = blockIdx.x - 32;
    const int bchunk = (lin & 7) * 256 + (lin >> 3); // XCD-contiguous rows
    const int row = bchunk * 4 + w;
    const int s = row & (S_LEN - 1);
    const int b = row >> 12;
    if (l < K_R) {
      r_s[w][l] = routes[s * K_R + l];
      w_s[w][l] = fw[s * K_R + l];
    }
    __syncthreads();
    const __hip_bfloat16* xbb = xb + (size_t)b * S_LEN * D_DIM + l * 8;
    float acc[8] = {};
#pragma unroll 8
    for (int k = 0; k < K_R; ++k) {
      const float wk = w_s[w][k];
      const bf16x8 v = *(const bf16x8*)(xbb + (size_t)r_s[w][k] * D_DIM);
#pragma unroll
      for (int j = 0; j < 8; ++j) acc[j] = fmaf(wk, bf2f(v[j]), acc[j]);
    }
    union { __hip_bfloat16 h[8]; int4 v; } u;
#pragma unroll
    for (int j = 0; j < 8; ++j) u.h[j] = __float2bfloat16(acc[j]);
    *(int4*)(g + (size_t)row * D_DIM + l * 8) = u.v;
    return;
  }

  // ---- wcgemm path: WcT[j][q] = sum_p WoutTb[j][p] * Winb[q][p] ----
  const int id2 = blockIdx.x;           // [0,32)
  const int bm0 = (id2 >> 3) * BM;
  const int bn0 = (id2 & 7) * BN;
  const int wr  = (w >> 1) * 64;
  const int wcn = (w & 1) * 32;

  const int rin = l >> 3;
  const int usw = (l & 7) ^ rin;
  const __hip_bfloat16* gA = WoutTb + (size_t)(bm0 + w * 8 + rin) * D_DIM + usw * 8;
  const __hip_bfloat16* gB = Winb   + (size_t)(bn0 + w * 8 + rin) * D_DIM + usw * 8;
  __hip_bfloat16* ldsA = &As[w * 8][0];
  __hip_bfloat16* ldsB = &Bs[w * 8][0];
  const int fr = l & 15, fq = l >> 4;

  f32x4 acc[4][2] = {};
  for (int k0 = 0; k0 < D_DIM; k0 += BK) {
#pragma unroll
    for (int i = 0; i < 4; ++i)
      gload_lds16(gA + (size_t)(i * 32) * D_DIM + k0, ldsA + i * 32 * BK);
#pragma unroll
    for (int j = 0; j < 2; ++j)
      gload_lds16(gB + (size_t)(j * 32) * D_DIM + k0, ldsB + j * 32 * BK);
    __syncthreads();
#pragma unroll
    for (int kk = 0; kk < 2; ++kk) {
      const int u = (kk * 4 + fq) ^ (fr & 7);
      bf16x8 af[4], bfv[2];
#pragma unroll
      for (int m = 0; m < 4; ++m)
        af[m] = *(const bf16x8*)&As[wr + m * 16 + fr][u * 8];
#pragma unroll
      for (int n = 0; n < 2; ++n)
        bfv[n] = *(const bf16x8*)&Bs[wcn + n * 16 + fr][u * 8];
#pragma unroll
      for (int m = 0; m < 4; ++m)
#pragma unroll
        for (int n = 0; n < 2; ++n)
          acc[m][n] = __builtin_amdgcn_mfma_f32_16x16x32_bf16(af[m], bfv[n], acc[m][n], 0, 0, 0);
    }
    __syncthreads();
  }
#pragma unroll
  for (int m = 0; m < 4; ++m)
#pragma unroll
    for (int n = 0; n < 2; ++n)
#pragma unroll
      for (int r = 0; r < 4; ++r) {
        const int grow = bm0 + wr + m * 16 + fq * 4 + r;
        const int gcol = bn0 + wcn + n * 16 + fr;
        WcT[(size_t)grow * D_DIM + gcol] = __float2bfloat16(acc[m][n][r]);
      }
}

// ---------------------------------------------------------------------------
// Kernel 3: out = x + g @ Wc + b_out   (M=8192, N=512, K=512)
//   3-deep counted-vmcnt pipeline (T4): STAGE(t+2) issued each iter; only
//   s_waitcnt vmcnt(6) + one raw s_barrier per K-step — next tile's 6 loads
//   stay in flight across the barrier (never drain to 0 in-loop).
// ---------------------------------------------------------------------------
__global__ void __launch_bounds__(256) gemm_out_kernel(
    const __hip_bfloat16* __restrict__ A,    // g (M x 512)
    const __hip_bfloat16* __restrict__ BT,   // WcT (n x k)
    const float* __restrict__ x,
    const float* __restrict__ b_out,
    float* __restrict__ out) {
  __shared__ __hip_bfloat16 As[3][BM][BK];   // 48 KB
  __shared__ __hip_bfloat16 Bs[3][BN][BK];   // 24 KB  (72 KB -> 2 blocks/CU)
  const int tid = threadIdx.x;
  const int w = tid >> 6, l = tid & 63;

  const int lin = blockIdx.x;
  const int id2 = (lin & 7) * 64 + (lin >> 3);
  const int bm0 = (id2 >> 3) * BM;
  const int bn0 = (id2 & 7) * BN;

  const int wr  = (w >> 1) * 64;
  const int wcn = (w & 1) * 32;

  const int rin = l >> 3;
  const int usw = (l & 7) ^ rin;
  const __hip_bfloat16* gA = A + (size_t)(bm0 + w * 8 + rin) * D_DIM + usw * 8;
  const __hip_bfloat16* gB = BT + (size_t)(bn0 + w * 8 + rin) * D_DIM + usw * 8;

  const int fr = l & 15, fq = l >> 4;
  f32x4 acc[4][2] = {};

#define STAGE(buf, k0)                                                          \
  {                                                                             \
    _Pragma("unroll")                                                           \
    for (int i = 0; i < 4; ++i)                                                 \
      gload_lds16(gA + (size_t)(i * 32) * D_DIM + (k0),                         \
                  &As[buf][w * 8][0] + i * 32 * BK);                            \
    _Pragma("unroll")                                                           \
    for (int j = 0; j < 2; ++j)                                                 \
      gload_lds16(gB + (size_t)(j * 32) * D_DIM + (k0),                         \
                  &Bs[buf][w * 8][0] + j * 32 * BK);                            \
  }

#define COMPUTE(buf)                                                            \
  {                                                                             \
    _Pragma("unroll")                                                           \
    for (int kk = 0; kk < 2; ++kk) {                                            \
      const int u = (kk * 4 + fq) ^ (fr & 7);                                   \
      bf16x8 af[4], bfv[2];                                                     \
      _Pragma("unroll")                                                         \
      for (int m = 0; m < 4; ++m)                                               \
        af[m] = *(const bf16x8*)&As[buf][wr + m * 16 + fr][u * 8];              \
      _Pragma("unroll")                                                         \
      for (int n = 0; n < 2; ++n)                                               \
        bfv[n] = *(const bf16x8*)&Bs[buf][wcn + n * 16 + fr][u * 8];            \
      _Pragma("unroll")                                                         \
      for (int m = 0; m < 4; ++m)                                               \
        _Pragma("unroll")                                                       \
        for (int n = 0; n < 2; ++n)                                             \
          acc[m][n] = __builtin_amdgcn_mfma_f32_16x16x32_bf16(                  \
              af[m], bfv[n], acc[m][n], 0, 0, 0);                               \
    }                                                                           \
  }

  // prologue: two tiles in flight (12 outstanding VMEM ops/wave)
  STAGE(0, 0);
  STAGE(1, BK);
#pragma unroll
  for (int t = 0; t < 7; ++t) {
    // wait for tile t only (tile t+1's 6 loads stay in flight)
    asm volatile("s_waitcnt vmcnt(6)" ::: "memory");
    __builtin_amdgcn_s_barrier();
    __builtin_amdgcn_sched_barrier(0);
    if (t < 6) STAGE((t + 2) % 3, (t + 2) * BK);   // issue before compute
    COMPUTE(t % 3);
  }
  // tail: tile 7
  asm volatile("s_waitcnt vmcnt(0)" ::: "memory");
  __builtin_amdgcn_s_barrier();
  __builtin_amdgcn_sched_barrier(0);
  COMPUTE(1);   // 7 % 3
#undef STAGE
#undef COMPUTE

  const float bb0 = b_out[bn0 + wcn + fr];
  const float bb1 = b_out[bn0 + wcn + 16 + fr];
#pragma unroll
  for (int m = 0; m < 4; ++m)
#pragma unroll
    for (int r = 0; r < 4; ++r) {
      const int grow = bm0 + wr + m * 16 + fq * 4 + r;
      const size_t base = (size_t)grow * D_DIM + bn0 + wcn + fr;
      out[base]      = acc[m][0][r] + x[base]      + bb0;
      out[base + 16] = acc[m][1][r] + x[base + 16] + bb1;
    }
}

// ---------------------------------------------------------------------------
extern "C" void kernel_launch(void* const* d_in, const int* in_sizes, int n_in,
                              void* d_out, int out_size, void* d_ws, size_t ws_size,
                              hipStream_t stream) {
  const float* x      = (const float*)d_in[0];
  const float* W_in   = (const float*)d_in[1];
  const float* W_out  = (const float*)d_in[2];
  const float* b_out  = (const float*)d_in[3];
  const float* fw     = (const float*)d_in[4];
  const int*   routes = (const int*)d_in[5];
  float* out = (float*)d_out;

  // workspace: Xb(8MB) | WcT(512KB) | g(8MB) | Winb(512KB) | WoutTb(512KB)
  char* ws = (char*)d_ws;
  __hip_bfloat16* Xb     = (__hip_bfloat16*)ws;
  __hip_bfloat16* WcT    = (__hip_bfloat16*)(ws + 8388608);
  __hip_bfloat16* g      = (__hip_bfloat16*)(ws + 8912896);
  __hip_bfloat16* Winb   = (__hip_bfloat16*)(ws + 17301504);
  __hip_bfloat16* WoutTb = (__hip_bfloat16*)(ws + 17825792);

  // 1) casts + transpose (R4-proven)
  prep_kernel<<<2176, 256, 0, stream>>>(x, Xb, W_in, Winb, W_out, WoutTb);
  // 2) wcgemm (32 blocks, first) || gather (2048 blocks)  (R4-proven)
  mid_kernel<<<2080, 256, 0, stream>>>(Xb, fw, routes, g, WoutTb, Winb, WcT);
  // 3) out = x + g @ Wc + b_out  (3-deep counted-vmcnt pipeline)
  gemm_out_kernel<<<512, 256, 0, stream>>>(g, WcT, x, b_out, out);
}